// Round 1
// baseline (9262.326 us; speedup 1.0000x reference)
//
#include <hip/hip_runtime.h>
#include <stdint.h>

#define SEQ 48
#define NB  16
#define NL  16
#define NV  32000

typedef short bf16x8 __attribute__((ext_vector_type(8)));
typedef float f32x4  __attribute__((ext_vector_type(4)));

__device__ __forceinline__ unsigned short f2b(float f) {
    union { float f; unsigned int u; } v; v.f = f;
    unsigned int r = (v.u + 0x7FFFu + ((v.u >> 16) & 1u)) >> 16;
    return (unsigned short)r;
}
__device__ __forceinline__ float b2f(unsigned short s) {
    union { float f; unsigned int u; } v; v.u = ((unsigned int)s) << 16;
    return v.f;
}
// load 8 consecutive fp32, round to bf16 fragment
__device__ __forceinline__ bf16x8 load_w8(const float* p) {
    const float4* q = (const float4*)p;
    float4 a = q[0], b = q[1];
    bf16x8 r;
    r[0] = (short)f2b(a.x); r[1] = (short)f2b(a.y);
    r[2] = (short)f2b(a.z); r[3] = (short)f2b(a.w);
    r[4] = (short)f2b(b.x); r[5] = (short)f2b(b.y);
    r[6] = (short)f2b(b.z); r[7] = (short)f2b(b.w);
    return r;
}
__device__ __forceinline__ bf16x8 load_b8(const unsigned short* p) {
    return *(const bf16x8*)p;   // 16B aligned by construction
}
__device__ __forceinline__ f32x4 mfma16(bf16x8 a, bf16x8 b, f32x4 c) {
    return __builtin_amdgcn_mfma_f32_16x16x32_bf16(a, b, c, 0, 0, 0);
}
__device__ __forceinline__ float sigm(float x) { return 1.0f / (1.0f + __expf(-x)); }
__device__ __forceinline__ float tanh_(float x) { return 1.0f - 2.0f / (__expf(2.0f * x) + 1.0f); }

// ---------------- embeddings: gather + bf16 ----------------
__global__ __launch_bounds__(256) void embed_kernel(
    const int* __restrict__ x, const int* __restrict__ y,
    const float* __restrict__ enc_emb, const float* __restrict__ dec_emb,
    unsigned short* __restrict__ xs, unsigned short* __restrict__ ds)
{
    int bid = blockIdx.x;             // 0..1535
    int which = bid >= 768;
    int r = which ? bid - 768 : bid;
    int t = r >> 4, b = r & 15;
    int tok = which ? y[b * SEQ + t] : x[b * SEQ + t];
    const float* src = (which ? dec_emb : enc_emb) + (size_t)tok * 512;
    unsigned short* dst = (which ? ds : xs) + ((size_t)t * 16 + b) * 512;
    for (int k = threadIdx.x; k < 512; k += 256) dst[k] = f2b(src[k]);
}

// ---------------- input GEMM: Gin[768][2048] = Xbf[768][512] @ W[2048][512]^T + bias ----------------
__global__ __launch_bounds__(256) void input_gemm(
    const unsigned short* __restrict__ X,
    const float* __restrict__ W,
    const float* __restrict__ bias,
    float* __restrict__ Gout)
{
    const int tid = threadIdx.x;
    const int mt = blockIdx.x, nt = blockIdx.y;   // 12 x 32
    const int w = tid >> 6, lane = tid & 63, q = lane >> 4, ln = lane & 15;
    const int m0 = mt * 64 + w * 16;
    const int n0 = nt * 64;
    f32x4 acc[4];
#pragma unroll
    for (int j = 0; j < 4; ++j) acc[j] = (f32x4){0.f, 0.f, 0.f, 0.f};
#pragma unroll 4
    for (int kt = 0; kt < 16; ++kt) {
        bf16x8 a = load_b8(X + ((size_t)m0 + ln) * 512 + kt * 32 + q * 8);
#pragma unroll
        for (int j = 0; j < 4; ++j) {
            bf16x8 b = load_w8(W + ((size_t)(n0 + j * 16 + ln)) * 512 + kt * 32 + q * 8);
            acc[j] = mfma16(a, b, acc[j]);
        }
    }
#pragma unroll
    for (int j = 0; j < 4; ++j) {
        int n = n0 + j * 16 + ln;
        float bv = bias[n];
#pragma unroll
        for (int r = 0; r < 4; ++r)
            Gout[((size_t)(m0 + q * 4 + r)) * 2048 + n] = acc[j][r] + bv;
    }
}

// ---------------- encoder recurrent layer: 16 WGs x 256 thr ----------------
// WG: dir = bid>>3, p = bid&7 owns hidden units [32p,32p+32). wave w = gate w.
__global__ __launch_bounds__(256) void enc_rec(
    const float* __restrict__ Whh,          // [NL][2][1024][256]
    const float* __restrict__ Gin,          // [768][2048]
    unsigned short* __restrict__ xs_out,    // [48][16][512]
    unsigned short* __restrict__ dec_h0,    // [NL][16][512]
    float* __restrict__ dec_c0,
    int* __restrict__ flags, int l)
{
    const int tid = threadIdx.x, bid = blockIdx.x;
    const int dir = bid >> 3, p = bid & 7;
    const int w = tid >> 6, lane = tid & 63, q = lane >> 4, ln = lane & 15;

    __shared__ float gsm[4][32][19];
    __shared__ float cbuf[32][19];

    bf16x8 afr[2][8];
    {
        const float* wbase = Whh + ((size_t)(l * 2 + dir) * 1024 + (w * 256 + p * 32)) * 256;
#pragma unroll
        for (int rt = 0; rt < 2; ++rt)
#pragma unroll
            for (int kt = 0; kt < 8; ++kt)
                afr[rt][kt] = load_w8(wbase + (size_t)(rt * 16 + ln) * 256 + kt * 32 + q * 8);
    }
    int* myflag = flags + bid * 16;

    for (int t = 0; t < SEQ; ++t) {
        const int t_src = dir ? (SEQ - 1 - t) : t;
        f32x4 acc[2][2];
#pragma unroll
        for (int rt = 0; rt < 2; ++rt) { acc[rt][0] = (f32x4){0.f,0.f,0.f,0.f}; acc[rt][1] = (f32x4){0.f,0.f,0.f,0.f}; }

        if (t > 0) {
            if (tid < 8) {
                int* f = flags + (dir * 8 + tid) * 16;
                int iter = 0;
                while (__hip_atomic_load(f, __ATOMIC_ACQUIRE, __HIP_MEMORY_SCOPE_AGENT) < t) {
                    __builtin_amdgcn_s_sleep(2);
                    if (++iter > 2000000) break;
                }
            }
            __syncthreads();
            const int prev_src = dir ? (t_src + 1) : (t_src - 1);
            const unsigned short* hbase = xs_out + ((size_t)prev_src * 16 + ln) * 512 + dir * 256;
#pragma unroll
            for (int kt = 0; kt < 8; ++kt) {
                bf16x8 bfr = load_b8(hbase + kt * 32 + q * 8);
                acc[0][kt & 1] = mfma16(afr[0][kt], bfr, acc[0][kt & 1]);
                acc[1][kt & 1] = mfma16(afr[1][kt], bfr, acc[1][kt & 1]);
            }
        }
        {
            const float* gin_row = Gin + ((size_t)t_src * 16 + ln) * 2048 + dir * 1024 + w * 256 + p * 32;
#pragma unroll
            for (int rt = 0; rt < 2; ++rt) {
                const float4 gv = *(const float4*)(gin_row + rt * 16 + q * 4);
                gsm[w][rt * 16 + q * 4 + 0][ln] = gv.x + acc[rt][0][0] + acc[rt][1][0];
                gsm[w][rt * 16 + q * 4 + 1][ln] = gv.y + acc[rt][0][1] + acc[rt][1][1];
                gsm[w][rt * 16 + q * 4 + 2][ln] = gv.z + acc[rt][0][2] + acc[rt][1][2];
                gsm[w][rt * 16 + q * 4 + 3][ln] = gv.w + acc[rt][0][3] + acc[rt][1][3];
            }
        }
        __syncthreads();
        {
            const int b = tid & 15, up = tid >> 4;     // 2 units per thread
            unsigned int hv = 0;
#pragma unroll
            for (int s = 0; s < 2; ++s) {
                int u = up * 2 + s;
                float gi = gsm[0][u][b], gf = gsm[1][u][b], gg = gsm[2][u][b], go = gsm[3][u][b];
                float c = (t == 0) ? 0.f : cbuf[u][b];
                float cn = sigm(gf) * c + sigm(gi) * tanh_(gg);
                float h = sigm(go) * tanh_(cn);
                cbuf[u][b] = cn;
                hv |= ((unsigned int)f2b(h)) << (16 * s);
                if (t == SEQ - 1) dec_c0[((size_t)l * 16 + b) * 512 + dir * 256 + p * 32 + u] = cn;
            }
            size_t off = ((size_t)t_src * 16 + b) * 512 + dir * 256 + p * 32 + up * 2;
            __hip_atomic_store((unsigned int*)(xs_out + off), hv, __ATOMIC_RELAXED, __HIP_MEMORY_SCOPE_AGENT);
            if (t == SEQ - 1)
                *(unsigned int*)(dec_h0 + ((size_t)l * 16 + b) * 512 + dir * 256 + p * 32 + up * 2) = hv;
        }
        __syncthreads();
        if (tid == 0)
            __hip_atomic_store(myflag, t + 1, __ATOMIC_RELEASE, __HIP_MEMORY_SCOPE_AGENT);
    }
}

// ---------------- decoder recurrent layer: 16 WGs x 512 thr ----------------
// WG p owns units [32p,32p+32). wave w: gate = w>>1, row-half = w&1.
__global__ __launch_bounds__(512) void dec_rec(
    const float* __restrict__ Whh,          // [NL][2048][512]
    const float* __restrict__ Gin,          // [768][2048]
    const unsigned short* __restrict__ h0,  // [16][512] (layer slice)
    const float* __restrict__ c0,           // [16][512]
    unsigned short* __restrict__ ds_out,    // [48][16][512]
    int* __restrict__ flags, int l)
{
    const int tid = threadIdx.x, bid = blockIdx.x;
    const int p = bid;
    const int w = tid >> 6, lane = tid & 63, q = lane >> 4, ln = lane & 15;
    const int gate = w >> 1, rh = w & 1;

    __shared__ float gsm[4][32][19];
    __shared__ float cbuf[32][19];

    bf16x8 afr[16];
    {
        const float* wbase = Whh + ((size_t)l * 2048 + gate * 512 + p * 32 + rh * 16 + ln) * 512;
#pragma unroll
        for (int kt = 0; kt < 16; ++kt)
            afr[kt] = load_w8(wbase + kt * 32 + q * 8);
    }
    int* myflag = flags + bid * 16;

    for (int t = 0; t < SEQ; ++t) {
        if (t > 0) {
            if (tid < 16) {
                int* f = flags + tid * 16;
                int iter = 0;
                while (__hip_atomic_load(f, __ATOMIC_ACQUIRE, __HIP_MEMORY_SCOPE_AGENT) < t) {
                    __builtin_amdgcn_s_sleep(2);
                    if (++iter > 2000000) break;
                }
            }
            __syncthreads();
        }
        const unsigned short* hbase = (t == 0) ? (h0 + (size_t)ln * 512)
                                               : (ds_out + ((size_t)(t - 1) * 16 + ln) * 512);
        f32x4 acc0 = (f32x4){0.f,0.f,0.f,0.f}, acc1 = (f32x4){0.f,0.f,0.f,0.f};
#pragma unroll
        for (int kt = 0; kt < 16; kt += 2) {
            bf16x8 b0 = load_b8(hbase + kt * 32 + q * 8);
            bf16x8 b1 = load_b8(hbase + (kt + 1) * 32 + q * 8);
            acc0 = mfma16(afr[kt], b0, acc0);
            acc1 = mfma16(afr[kt + 1], b1, acc1);
        }
        {
            const float* gin_row = Gin + ((size_t)t * 16 + ln) * 2048 + gate * 512 + p * 32 + rh * 16;
            const float4 gv = *(const float4*)(gin_row + q * 4);
            gsm[gate][rh * 16 + q * 4 + 0][ln] = gv.x + acc0[0] + acc1[0];
            gsm[gate][rh * 16 + q * 4 + 1][ln] = gv.y + acc0[1] + acc1[1];
            gsm[gate][rh * 16 + q * 4 + 2][ln] = gv.z + acc0[2] + acc1[2];
            gsm[gate][rh * 16 + q * 4 + 3][ln] = gv.w + acc0[3] + acc1[3];
        }
        __syncthreads();
        if (tid < 256) {
            const int b = tid & 15, up = tid >> 4;   // 2 units per thread
            unsigned int hv = 0;
#pragma unroll
            for (int s = 0; s < 2; ++s) {
                int u = up * 2 + s;
                float gi = gsm[0][u][b], gf = gsm[1][u][b], gg = gsm[2][u][b], go = gsm[3][u][b];
                float c = (t == 0) ? c0[(size_t)b * 512 + p * 32 + u] : cbuf[u][b];
                float cn = sigm(gf) * c + sigm(gi) * tanh_(gg);
                float h = sigm(go) * tanh_(cn);
                cbuf[u][b] = cn;
                hv |= ((unsigned int)f2b(h)) << (16 * s);
            }
            size_t off = ((size_t)t * 16 + b) * 512 + p * 32 + up * 2;
            __hip_atomic_store((unsigned int*)(ds_out + off), hv, __ATOMIC_RELAXED, __HIP_MEMORY_SCOPE_AGENT);
        }
        __syncthreads();
        if (tid == 0)
            __hip_atomic_store(myflag, t + 1, __ATOMIC_RELEASE, __HIP_MEMORY_SCOPE_AGENT);
    }
}

// ---------------- final projection: ltmp[768][32000] bf16 = ds @ lin_W^T + lin_b ----------------
__global__ __launch_bounds__(256) void final_gemm(
    const unsigned short* __restrict__ ds,
    const float* __restrict__ W,
    const float* __restrict__ bias,
    unsigned short* __restrict__ out)
{
    const int tid = threadIdx.x;
    const int w = tid >> 6, lane = tid & 63, q = lane >> 4, ln = lane & 15;
    const int n0 = blockIdx.x * 64;     // 500 blocks
    for (int mb = 0; mb < 12; ++mb) {
        const int m0 = mb * 64 + w * 16;
        bf16x8 afr[16];
#pragma unroll
        for (int kt = 0; kt < 16; ++kt)
            afr[kt] = load_b8(ds + ((size_t)m0 + ln) * 512 + kt * 32 + q * 8);
#pragma unroll
        for (int j = 0; j < 4; ++j) {
            f32x4 acc0 = (f32x4){0.f,0.f,0.f,0.f}, acc1 = (f32x4){0.f,0.f,0.f,0.f};
            const float* wb = W + ((size_t)(n0 + j * 16 + ln)) * 512;
#pragma unroll
            for (int kt = 0; kt < 16; kt += 2) {
                bf16x8 b0 = load_w8(wb + kt * 32 + q * 8);
                bf16x8 b1 = load_w8(wb + (kt + 1) * 32 + q * 8);
                acc0 = mfma16(afr[kt], b0, acc0);
                acc1 = mfma16(afr[kt + 1], b1, acc1);
            }
            int n = n0 + j * 16 + ln;
            float bv = bias[n];
#pragma unroll
            for (int r = 0; r < 4; ++r)
                out[((size_t)m0 + q * 4 + r) * NV + n] = f2b(acc0[r] + acc1[r] + bv);
        }
    }
}

// ---------------- transpose: out[b][v][t] (fp32) from ltmp[t*16+b][v] (bf16) ----------------
__global__ __launch_bounds__(256) void transpose_out(
    const unsigned short* __restrict__ tmp, float* __restrict__ out)
{
    __shared__ unsigned short lds[256 * 50];
    const int tid = threadIdx.x;
    const int vb = blockIdx.x % 125, b = blockIdx.x / 125;
    const int v0 = vb * 256;
    for (int tt = 0; tt < SEQ; ++tt)
        lds[tid * 50 + tt] = tmp[((size_t)tt * 16 + b) * NV + v0 + tid];
    __syncthreads();
    float* ob = out + ((size_t)b * NV + v0 + tid) * SEQ;
#pragma unroll
    for (int t4 = 0; t4 < 12; ++t4) {
        float4 v;
        v.x = b2f(lds[tid * 50 + t4 * 4 + 0]);
        v.y = b2f(lds[tid * 50 + t4 * 4 + 1]);
        v.z = b2f(lds[tid * 50 + t4 * 4 + 2]);
        v.w = b2f(lds[tid * 50 + t4 * 4 + 3]);
        *(float4*)(ob + t4 * 4) = v;
    }
}

extern "C" void kernel_launch(void* const* d_in, const int* in_sizes, int n_in,
                              void* d_out, int out_size, void* d_ws, size_t ws_size,
                              hipStream_t stream)
{
    const int*   x       = (const int*)d_in[0];
    const int*   y       = (const int*)d_in[1];
    const float* enc_emb = (const float*)d_in[2];
    const float* enc_Wih = (const float*)d_in[3];
    const float* enc_Whh = (const float*)d_in[4];
    const float* enc_bb  = (const float*)d_in[5];
    const float* dec_emb = (const float*)d_in[6];
    const float* dec_Wih = (const float*)d_in[7];
    const float* dec_Whh = (const float*)d_in[8];
    const float* dec_bb  = (const float*)d_in[9];
    const float* lin_W   = (const float*)d_in[10];
    const float* lin_b   = (const float*)d_in[11];
    float* out = (float*)d_out;

    char* ws = (char*)d_ws;
    int* flags              = (int*)ws;                                   // 32 KB
    unsigned short* xsA     = (unsigned short*)(ws + 32768);              // 768 KB each
    unsigned short* xsB     = (unsigned short*)(ws + 32768 + 786432);
    unsigned short* xsC     = (unsigned short*)(ws + 32768 + 2 * 786432);
    float* Gin              = (float*)(ws + 32768 + 3 * 786432);          // 6 MB
    unsigned short* dech0   = (unsigned short*)(ws + 32768 + 3 * 786432 + 6291456);
    float* decc0            = (float*)(ws + 32768 + 3 * 786432 + 6291456 + 262144);
    unsigned short* ltmp    = (unsigned short*)(ws + 32768 + 3 * 786432 + 6291456 + 262144 + 524288);

    hipMemsetAsync(flags, 0, 32768, stream);
    embed_kernel<<<1536, 256, 0, stream>>>(x, y, enc_emb, dec_emb, xsA, xsC);

    for (int l = 0; l < NL; ++l) {
        unsigned short* xin  = (l & 1) ? xsB : xsA;
        unsigned short* xout = (l & 1) ? xsA : xsB;
        input_gemm<<<dim3(12, 32), 256, 0, stream>>>(
            xin, enc_Wih + (size_t)l * 2 * 1024 * 512, enc_bb + (size_t)l * 2048, Gin);
        enc_rec<<<16, 256, 0, stream>>>(enc_Whh, Gin, xout, dech0, decc0, flags + l * 256, l);
    }
    for (int l = 0; l < NL; ++l) {
        unsigned short* din  = (l & 1) ? xsB : xsC;
        unsigned short* dout = (l & 1) ? xsC : xsB;
        input_gemm<<<dim3(12, 32), 256, 0, stream>>>(
            din, dec_Wih + (size_t)l * 2048 * 512, dec_bb + (size_t)l * 2048, Gin);
        dec_rec<<<16, 512, 0, stream>>>(dec_Whh, Gin,
            dech0 + (size_t)l * 16 * 512, decc0 + (size_t)l * 16 * 512, dout,
            flags + 4096 + l * 256, l);
    }
    final_gemm<<<500, 256, 0, stream>>>(xsC, lin_W, lin_b, ltmp);
    transpose_out<<<2000, 256, 0, stream>>>(ltmp, out);
}

// Round 2
// 5241.631 us; speedup vs baseline: 1.7671x; 1.7671x over previous
//
#include <hip/hip_runtime.h>
#include <stdint.h>

#define SEQ 48
#define NL  16
#define NV  32000
#define POLLMAX 4000000

typedef short bf16x8 __attribute__((ext_vector_type(8)));
typedef float f32x4  __attribute__((ext_vector_type(4)));

__device__ __forceinline__ unsigned short f2b(float f) {
    union { float f; unsigned int u; } v; v.f = f;
    unsigned int r = (v.u + 0x7FFFu + ((v.u >> 16) & 1u)) >> 16;
    return (unsigned short)r;
}
__device__ __forceinline__ float b2f(unsigned short s) {
    union { float f; unsigned int u; } v; v.u = ((unsigned int)s) << 16;
    return v.f;
}
__device__ __forceinline__ bf16x8 load_w8(const float* p) {
    const float4* q = (const float4*)p;
    float4 a = q[0], b = q[1];
    bf16x8 r;
    r[0] = (short)f2b(a.x); r[1] = (short)f2b(a.y);
    r[2] = (short)f2b(a.z); r[3] = (short)f2b(a.w);
    r[4] = (short)f2b(b.x); r[5] = (short)f2b(b.y);
    r[6] = (short)f2b(b.z); r[7] = (short)f2b(b.w);
    return r;
}
__device__ __forceinline__ bf16x8 load_b8(const unsigned short* p) {
    return *(const bf16x8*)p;
}
__device__ __forceinline__ f32x4 mfma16(bf16x8 a, bf16x8 b, f32x4 c) {
    return __builtin_amdgcn_mfma_f32_16x16x32_bf16(a, b, c, 0, 0, 0);
}
__device__ __forceinline__ float sigm(float x) { return 1.0f / (1.0f + __expf(-x)); }
__device__ __forceinline__ float tanh_(float x) { return 1.0f - 2.0f / (__expf(2.0f * x) + 1.0f); }

// ---------------- embeddings: gather + bf16 ----------------
__global__ __launch_bounds__(256) void embed_kernel(
    const int* __restrict__ x, const int* __restrict__ y,
    const float* __restrict__ enc_emb, const float* __restrict__ dec_emb,
    unsigned short* __restrict__ xs, unsigned short* __restrict__ ds)
{
    int bid = blockIdx.x;             // 0..1535
    int which = bid >= 768;
    int r = which ? bid - 768 : bid;
    int t = r >> 4, b = r & 15;
    int tok = which ? y[b * SEQ + t] : x[b * SEQ + t];
    const float* src = (which ? dec_emb : enc_emb) + (size_t)tok * 512;
    unsigned short* dst = (which ? ds : xs) + ((size_t)t * 16 + b) * 512;
    for (int k = threadIdx.x; k < 512; k += 256) dst[k] = f2b(src[k]);
}

// ---------------- full encoder in one kernel: 32 WGs (dir*16 + p), loops layers ----------------
// WG owns 16 hidden units of its direction; wave = gate; folds W_ih into the step.
__global__ __launch_bounds__(256, 2) void enc_all(
    const float* __restrict__ Wih,   // [NL][2][1024][512]
    const float* __restrict__ Whh,   // [NL][2][1024][256]
    const float* __restrict__ bias,  // [NL][2][1024]
    unsigned short* __restrict__ xsA, unsigned short* __restrict__ xsB,  // [48][16][512] ping-pong
    unsigned short* __restrict__ dec_h0,  // [NL][16][512]
    float* __restrict__ dec_c0,           // [NL][16][512]
    int* __restrict__ flags)              // [NL][32] stride 16 ints
{
    const int tid = threadIdx.x, bid = blockIdx.x;
    const int dir = bid >> 4, p = bid & 15;
    const int gate = tid >> 6, lane = tid & 63, q = lane >> 4, ln = lane & 15;
    __shared__ float gsm[4][16][17];
    __shared__ float cbuf[16][17];

    for (int l = 0; l < NL; ++l) {
        const unsigned short* xin = (l & 1) ? xsB : xsA;
        unsigned short* xout = (l & 1) ? xsA : xsB;
        if (l > 0) {
            // wait until ALL 32 WGs finished layer l-1 (xin fully written)
            if (tid < 64) {
                if (tid < 32) {
                    const int* f = flags + ((l - 1) * 32 + tid) * 16;
                    int it = 0;
                    while (__hip_atomic_load(f, __ATOMIC_RELAXED, __HIP_MEMORY_SCOPE_AGENT) < SEQ)
                        if (++it > POLLMAX) break;
                }
                __builtin_amdgcn_fence(__ATOMIC_ACQUIRE, "agent");
            }
            __syncthreads();
        }
        // per-layer weights into registers (bf16 fragments)
        bf16x8 aih[16], ahh[8];
        {
            const float* wb = Wih + (((size_t)(l * 2 + dir) * 1024) + gate * 256 + p * 16 + ln) * 512;
#pragma unroll
            for (int kt = 0; kt < 16; ++kt) aih[kt] = load_w8(wb + kt * 32 + q * 8);
        }
        {
            const float* wb = Whh + (((size_t)(l * 2 + dir) * 1024) + gate * 256 + p * 16 + ln) * 256;
#pragma unroll
            for (int kt = 0; kt < 8; ++kt) ahh[kt] = load_w8(wb + kt * 32 + q * 8);
        }
        const float4 bias4 = *(const float4*)(bias + ((size_t)(l * 2 + dir) * 1024) + gate * 256 + p * 16 + q * 4);
        int* myflag = flags + (l * 32 + bid) * 16;

        for (int t = 0; t < SEQ; ++t) {
            const int t_src = dir ? (SEQ - 1 - t) : t;
            if (t > 0) {
                // wait own direction's 16 WGs to finish step t-1 (relaxed polls, one acquire fence)
                if (tid < 64) {
                    if (tid < 16) {
                        const int* f = flags + (l * 32 + dir * 16 + tid) * 16;
                        int it = 0;
                        while (__hip_atomic_load(f, __ATOMIC_RELAXED, __HIP_MEMORY_SCOPE_AGENT) < t)
                            if (++it > POLLMAX) break;
                    }
                    __builtin_amdgcn_fence(__ATOMIC_ACQUIRE, "agent");
                }
                __syncthreads();
            }
            f32x4 acc0 = {0.f,0.f,0.f,0.f}, acc1 = {0.f,0.f,0.f,0.f};
            const unsigned short* xrow = xin + ((size_t)t_src * 16 + ln) * 512;
#pragma unroll
            for (int kt = 0; kt < 16; kt += 2) {
                acc0 = mfma16(aih[kt],     load_b8(xrow + kt * 32 + q * 8),       acc0);
                acc1 = mfma16(aih[kt + 1], load_b8(xrow + (kt + 1) * 32 + q * 8), acc1);
            }
            if (t > 0) {
                const int prev_src = dir ? (t_src + 1) : (t_src - 1);
                const unsigned short* hrow = xout + ((size_t)prev_src * 16 + ln) * 512 + dir * 256;
#pragma unroll
                for (int kt = 0; kt < 8; kt += 2) {
                    acc0 = mfma16(ahh[kt],     load_b8(hrow + kt * 32 + q * 8),       acc0);
                    acc1 = mfma16(ahh[kt + 1], load_b8(hrow + (kt + 1) * 32 + q * 8), acc1);
                }
            }
            gsm[gate][q * 4 + 0][ln] = acc0[0] + acc1[0] + bias4.x;
            gsm[gate][q * 4 + 1][ln] = acc0[1] + acc1[1] + bias4.y;
            gsm[gate][q * 4 + 2][ln] = acc0[2] + acc1[2] + bias4.z;
            gsm[gate][q * 4 + 3][ln] = acc0[3] + acc1[3] + bias4.w;
            __syncthreads();
            if (tid < 128) {
                const int b = tid >> 3, u2 = (tid & 7) * 2;
                unsigned int hv = 0;
#pragma unroll
                for (int s = 0; s < 2; ++s) {
                    int u = u2 + s;
                    float gi = gsm[0][u][b], gf = gsm[1][u][b], gg = gsm[2][u][b], go = gsm[3][u][b];
                    float c = (t == 0) ? 0.f : cbuf[u][b];
                    float cn = sigm(gf) * c + sigm(gi) * tanh_(gg);
                    float h = sigm(go) * tanh_(cn);
                    cbuf[u][b] = cn;
                    hv |= ((unsigned int)f2b(h)) << (16 * s);
                    if (t == SEQ - 1)
                        dec_c0[((size_t)l * 16 + b) * 512 + dir * 256 + p * 16 + u] = cn;
                }
                size_t off = ((size_t)t_src * 16 + b) * 512 + dir * 256 + p * 16 + u2;
                __hip_atomic_store((unsigned int*)(xout + off), hv, __ATOMIC_RELAXED, __HIP_MEMORY_SCOPE_AGENT);
                if (t == SEQ - 1)
                    *(unsigned int*)(dec_h0 + ((size_t)l * 16 + b) * 512 + dir * 256 + p * 16 + u2) = hv;
            }
            __syncthreads();
            if (tid == 0)
                __hip_atomic_store(myflag, t + 1, __ATOMIC_RELEASE, __HIP_MEMORY_SCOPE_AGENT);
        }
    }
}

// ---------------- pipelined decoder: ALL 16 layers concurrent, 512 WGs ----------------
// WG (l, p): units [16p,16p+16) of layer l; wave = gate. Wavefront dependency:
// (l,t) waits on (l-1,t) and (l,t-1). Critical path = 63 hops instead of 768.
__global__ __launch_bounds__(256, 2) void dec_pipe(
    const float* __restrict__ Wih,   // [NL][2048][512]
    const float* __restrict__ Whh,   // [NL][2048][512]
    const float* __restrict__ bias,  // [NL][2048]
    const unsigned short* __restrict__ demb, // [48][16][512]
    const unsigned short* __restrict__ h0,   // [NL][16][512]
    const float* __restrict__ c0,            // [NL][16][512]
    unsigned short* __restrict__ ds,         // [NL][48][16][512]
    int* __restrict__ flags)                 // [NL][32] stride 16 ints
{
    const int tid = threadIdx.x;
    const int l = blockIdx.x >> 5, p = blockIdx.x & 31;
    const int gate = tid >> 6, lane = tid & 63, q = lane >> 4, ln = lane & 15;
    __shared__ float gsm[4][16][17];
    __shared__ float cbuf[16][17];

    bf16x8 aih[16], ahh[16];
    const size_t row = (size_t)l * 2048 + gate * 512 + p * 16 + ln;
#pragma unroll
    for (int kt = 0; kt < 16; ++kt) aih[kt] = load_w8(Wih + row * 512 + kt * 32 + q * 8);
#pragma unroll
    for (int kt = 0; kt < 16; ++kt) ahh[kt] = load_w8(Whh + row * 512 + kt * 32 + q * 8);
    const float4 bias4 = *(const float4*)(bias + (size_t)l * 2048 + gate * 512 + p * 16 + q * 4);

    const unsigned short* xlayer = (l == 0) ? demb : (ds + (size_t)(l - 1) * SEQ * 16 * 512);
    const int* fin  = flags + (l - 1) * 32 * 16;
    const int* fown = flags + l * 32 * 16;
    int* myflag = flags + (l * 32 + p) * 16;

    for (int t = 0; t < SEQ; ++t) {
        if (tid < 64) {
            if (tid < 32) {
                if (l > 0) {   // input layer's step t complete
                    const int* f = fin + tid * 16;
                    int it = 0;
                    while (__hip_atomic_load(f, __ATOMIC_RELAXED, __HIP_MEMORY_SCOPE_AGENT) < t + 1)
                        if (++it > POLLMAX) break;
                }
            } else if (t > 0) {  // own layer's step t-1 complete (full h needed)
                const int* f = fown + (tid - 32) * 16;
                int it = 0;
                while (__hip_atomic_load(f, __ATOMIC_RELAXED, __HIP_MEMORY_SCOPE_AGENT) < t)
                    if (++it > POLLMAX) break;
            }
            __builtin_amdgcn_fence(__ATOMIC_ACQUIRE, "agent");
        }
        __syncthreads();

        const unsigned short* xrow = xlayer + ((size_t)t * 16 + ln) * 512;
        const unsigned short* hrow = (t == 0) ? (h0 + ((size_t)l * 16 + ln) * 512)
                                              : (ds + (((size_t)l * SEQ + (t - 1)) * 16 + ln) * 512);
        f32x4 acc0 = {0.f,0.f,0.f,0.f}, acc1 = {0.f,0.f,0.f,0.f};
#pragma unroll
        for (int kt = 0; kt < 16; kt += 2) {
            acc0 = mfma16(aih[kt],     load_b8(xrow + kt * 32 + q * 8),       acc0);
            acc1 = mfma16(aih[kt + 1], load_b8(xrow + (kt + 1) * 32 + q * 8), acc1);
        }
#pragma unroll
        for (int kt = 0; kt < 16; kt += 2) {
            acc0 = mfma16(ahh[kt],     load_b8(hrow + kt * 32 + q * 8),       acc0);
            acc1 = mfma16(ahh[kt + 1], load_b8(hrow + (kt + 1) * 32 + q * 8), acc1);
        }
        gsm[gate][q * 4 + 0][ln] = acc0[0] + acc1[0] + bias4.x;
        gsm[gate][q * 4 + 1][ln] = acc0[1] + acc1[1] + bias4.y;
        gsm[gate][q * 4 + 2][ln] = acc0[2] + acc1[2] + bias4.z;
        gsm[gate][q * 4 + 3][ln] = acc0[3] + acc1[3] + bias4.w;
        __syncthreads();
        if (tid < 128) {
            const int b = tid >> 3, u2 = (tid & 7) * 2;
            unsigned int hv = 0;
#pragma unroll
            for (int s = 0; s < 2; ++s) {
                int u = u2 + s;
                float gi = gsm[0][u][b], gf = gsm[1][u][b], gg = gsm[2][u][b], go = gsm[3][u][b];
                float c = (t == 0) ? c0[((size_t)l * 16 + b) * 512 + p * 16 + u] : cbuf[u][b];
                float cn = sigm(gf) * c + sigm(gi) * tanh_(gg);
                float h = sigm(go) * tanh_(cn);
                cbuf[u][b] = cn;
                hv |= ((unsigned int)f2b(h)) << (16 * s);
            }
            __hip_atomic_store((unsigned int*)(ds + (((size_t)l * SEQ + t) * 16 + b) * 512 + p * 16 + u2),
                               hv, __ATOMIC_RELAXED, __HIP_MEMORY_SCOPE_AGENT);
        }
        __syncthreads();
        if (tid == 0)
            __hip_atomic_store(myflag, t + 1, __ATOMIC_RELEASE, __HIP_MEMORY_SCOPE_AGENT);
    }
}

// ---------------- final projection: ltmp[768][32000] bf16 = ds15 @ lin_W^T + lin_b ----------------
__global__ __launch_bounds__(256) void final_gemm(
    const unsigned short* __restrict__ ds,
    const float* __restrict__ W,
    const float* __restrict__ bias,
    unsigned short* __restrict__ out)
{
    const int tid = threadIdx.x;
    const int w = tid >> 6, lane = tid & 63, q = lane >> 4, ln = lane & 15;
    const int n0 = blockIdx.x * 64;     // 500 blocks
    for (int mb = 0; mb < 12; ++mb) {
        const int m0 = mb * 64 + w * 16;
        bf16x8 afr[16];
#pragma unroll
        for (int kt = 0; kt < 16; ++kt)
            afr[kt] = load_b8(ds + ((size_t)m0 + ln) * 512 + kt * 32 + q * 8);
#pragma unroll
        for (int j = 0; j < 4; ++j) {
            f32x4 acc0 = {0.f,0.f,0.f,0.f}, acc1 = {0.f,0.f,0.f,0.f};
            const float* wb = W + ((size_t)(n0 + j * 16 + ln)) * 512;
#pragma unroll
            for (int kt = 0; kt < 16; kt += 2) {
                bf16x8 b0 = load_w8(wb + kt * 32 + q * 8);
                bf16x8 b1 = load_w8(wb + (kt + 1) * 32 + q * 8);
                acc0 = mfma16(afr[kt], b0, acc0);
                acc1 = mfma16(afr[kt + 1], b1, acc1);
            }
            int n = n0 + j * 16 + ln;
            float bv = bias[n];
#pragma unroll
            for (int r = 0; r < 4; ++r)
                out[((size_t)m0 + q * 4 + r) * NV + n] = f2b(acc0[r] + acc1[r] + bv);
        }
    }
}

// ---------------- transpose: out[b][v][t] (fp32) from ltmp[t*16+b][v] (bf16) ----------------
__global__ __launch_bounds__(256) void transpose_out(
    const unsigned short* __restrict__ tmp, float* __restrict__ out)
{
    __shared__ unsigned short lds[256 * 50];
    const int tid = threadIdx.x;
    const int vb = blockIdx.x % 125, b = blockIdx.x / 125;
    const int v0 = vb * 256;
    for (int tt = 0; tt < SEQ; ++tt)
        lds[tid * 50 + tt] = tmp[((size_t)tt * 16 + b) * NV + v0 + tid];
    __syncthreads();
    float* ob = out + ((size_t)b * NV + v0 + tid) * SEQ;
#pragma unroll
    for (int t4 = 0; t4 < 12; ++t4) {
        float4 v;
        v.x = b2f(lds[tid * 50 + t4 * 4 + 0]);
        v.y = b2f(lds[tid * 50 + t4 * 4 + 1]);
        v.z = b2f(lds[tid * 50 + t4 * 4 + 2]);
        v.w = b2f(lds[tid * 50 + t4 * 4 + 3]);
        *(float4*)(ob + t4 * 4) = v;
    }
}

extern "C" void kernel_launch(void* const* d_in, const int* in_sizes, int n_in,
                              void* d_out, int out_size, void* d_ws, size_t ws_size,
                              hipStream_t stream)
{
    const int*   x       = (const int*)d_in[0];
    const int*   y       = (const int*)d_in[1];
    const float* enc_emb = (const float*)d_in[2];
    const float* enc_Wih = (const float*)d_in[3];
    const float* enc_Whh = (const float*)d_in[4];
    const float* enc_bb  = (const float*)d_in[5];
    const float* dec_emb = (const float*)d_in[6];
    const float* dec_Wih = (const float*)d_in[7];
    const float* dec_Whh = (const float*)d_in[8];
    const float* dec_bb  = (const float*)d_in[9];
    const float* lin_W   = (const float*)d_in[10];
    const float* lin_b   = (const float*)d_in[11];
    float* out = (float*)d_out;

    char* ws = (char*)d_ws;
    int* flags            = (int*)ws;                                  // 64 KB (enc @0, dec @32KB)
    unsigned short* demb  = (unsigned short*)(ws + 65536);             // 768 KB
    unsigned short* xsA   = (unsigned short*)(ws + 65536 + 786432);
    unsigned short* xsB   = (unsigned short*)(ws + 65536 + 2 * 786432);
    unsigned short* dech0 = (unsigned short*)(ws + 65536 + 3 * 786432);            // 256 KB
    float* decc0          = (float*)(ws + 65536 + 3 * 786432 + 262144);            // 512 KB
    unsigned short* ds    = (unsigned short*)(ws + 65536 + 3 * 786432 + 262144 + 524288);   // 12 MB
    unsigned short* ltmp  = (unsigned short*)(ws + 65536 + 3 * 786432 + 262144 + 524288 + (size_t)16 * 786432);

    hipMemsetAsync(flags, 0, 65536, stream);
    embed_kernel<<<1536, 256, 0, stream>>>(x, y, enc_emb, dec_emb, xsA, demb);
    enc_all<<<32, 256, 0, stream>>>(enc_Wih, enc_Whh, enc_bb, xsA, xsB, dech0, decc0, flags);
    dec_pipe<<<512, 256, 0, stream>>>(dec_Wih, dec_Whh, dec_bb, demb, dech0, decc0, ds, flags + 8192);
    final_gemm<<<500, 256, 0, stream>>>(ds + (size_t)15 * SEQ * 16 * 512, lin_W, lin_b, ltmp);
    transpose_out<<<2000, 256, 0, stream>>>(ltmp, out);
}